// Round 1
// 24358.105 us; speedup vs baseline: 1.2869x; 1.2869x over previous
//
#include <hip/hip_runtime.h>
#include <stdint.h>
#include <stddef.h>

// LSTMNetwork: 3-layer stacked LSTM, batch=1, T=4096, IN=64, H=1024, OUT=1.
//
// Round 9: decouple the input GEMV (W_ih @ x) from the recurrence chain.
//   Round 8 (31.3ms = 7.64us/step) was latency-bound on the per-step
//   all-to-all broadcast: 8 poll groups (x+h rows) pre-barrier, 256
//   producers/row straggler convoy, 512 hot-row readers.
//   New structure:
//     - h-blocks: 128/layer, U=2 units/wave, registers hold ONLY w_hh
//       (128 floats/lane, same class as round 8). Critical loop stages just
//       the own-h row (4 groups), adds a precomputed gate preactivation
//       (one 64B line, loaded early, arrives with >=1 slot of slack).
//     - x-blocks: 128/layer (layers 1,2), compute W_ih@h_prev + biases into
//       full-history tagged preact buffers. No self-recurrence -> they
//       free-run on the upstream layer's lead; preacts are ready when the
//       h-blocks need them.
//   Epilogue: scatter-butterfly reduce (17 shuffles for 8 gate sums; lane l
//   ends with sum for acc l&7, matching per-lane bias/preact/slot layout),
//   bpermute gate gather, 2 h publishes per wave.
//   Grid 640 blocks @ __launch_bounds__(256,3) -> all co-resident (<=768).

#define T_STEPS 4096
#define HD      1024
#define RINGR   16
#define NBH     128        // h-blocks per layer

#define TAGL0 0x10000000u
#define TAGL1 0x30000000u
#define TAGL2 0x50000000u
#define TAGP1 0x70000000u
#define TAGP2 0x90000000u

typedef unsigned long long u64;

// Module .bss (~332 MB). Harness never pokes these.
__device__ u64 g_bufA[(size_t)T_STEPS * HD];    // layer0 h history (32 MB)
__device__ u64 g_bufB[(size_t)T_STEPS * HD];    // layer1 h history (32 MB)
__device__ u64 g_ring[RINGR * HD];              // layer2 h ring (128 KB)
__device__ u64 g_pre1[(size_t)T_STEPS * 4096];  // layer1 gate preacts (128 MB)
__device__ u64 g_pre2[(size_t)T_STEPS * 4096];  // layer2 gate preacts (128 MB)

__device__ __forceinline__ float fsig(float x)  { return 1.0f / (1.0f + __expf(-x)); }
__device__ __forceinline__ float ftanh(float x) { return 1.0f - 2.0f / (__expf(2.0f * x) + 1.0f); }

__global__ __launch_bounds__(256)
void zero_bufs()
{
    const size_t gtid = (size_t)blockIdx.x * blockDim.x + threadIdx.x;
    const size_t step = (size_t)gridDim.x * blockDim.x;
    for (size_t i = gtid; i < (size_t)T_STEPS * HD; i += step) { g_bufA[i] = 0ULL; g_bufB[i] = 0ULL; }
    for (size_t i = gtid; i < (size_t)RINGR * HD;  i += step) g_ring[i] = 0ULL;
    for (size_t i = gtid; i < (size_t)T_STEPS * 4096; i += step) { g_pre1[i] = 0ULL; g_pre2[i] = 0ULL; }
}

__global__ __launch_bounds__(256, 3)   // 640 blocks, 3 blocks/CU cap => all co-resident
void fused_scan(const float* __restrict__ seq,
                const float* __restrict__ wih0, const float* __restrict__ whh0_,
                const float* __restrict__ bih0, const float* __restrict__ bhh0,
                const float* __restrict__ wih1, const float* __restrict__ whh1_,
                const float* __restrict__ bih1, const float* __restrict__ bhh1,
                const float* __restrict__ wih2, const float* __restrict__ whh2_,
                const float* __restrict__ bih2, const float* __restrict__ bhh2)
{
    __shared__ float s_buf[2][HD];   // staged source row (own-h for h-role, x for x-role)

    const int bid  = blockIdx.x;
    const int lane = threadIdx.x & 63;
    const int wave = threadIdx.x >> 6;

    const bool isH  = (bid < 3 * NBH);
    const int layer = isH ? (bid >> 7) : (1 + ((bid - 3 * NBH) >> 7));
    const int bu    = isH ? (bid & (NBH - 1)) : ((bid - 3 * NBH) & (NBH - 1));
    const int j0    = bu * 8 + wave * 2;       // first of this wave's 2 units
    const int k     = lane & 7;                // acc index this lane finalizes (u*4+g)
    const int rk    = ((k & 3) << 10) + j0 + (k >> 2);   // its gate-row

    // ---- role pointers ----
    const float* Wmat;
    const u64*  srcBuf;  uint32_t srcTagB, srcRowM;
    u64*        hOut    = nullptr; uint32_t myTagB = 0, outRowM = 0xFFFFFFFFu;
    u64*        preOut  = nullptr; const u64* preIn = nullptr; uint32_t preTagB = 0;
    float       biasL   = 0.f;

    if (isH) {
        Wmat    = (layer == 0) ? whh0_ : (layer == 1) ? whh1_ : whh2_;
        hOut    = (layer == 0) ? g_bufA : (layer == 1) ? g_bufB : g_ring;
        myTagB  = (layer == 0) ? TAGL0 : (layer == 1) ? TAGL1 : TAGL2;
        outRowM = (layer == 2) ? (RINGR - 1) : 0xFFFFFFFFu;
        srcBuf  = hOut; srcTagB = myTagB; srcRowM = outRowM;   // own history
        if (layer == 1) { preIn = g_pre1; preTagB = TAGP1; }
        if (layer == 2) { preIn = g_pre2; preTagB = TAGP2; }
        if (layer == 0) biasL = bih0[rk] + bhh0[rk];
    } else {
        Wmat    = (layer == 1) ? wih1 : wih2;
        srcBuf  = (layer == 1) ? g_bufA : g_bufB;
        srcTagB = (layer == 1) ? TAGL0 : TAGL1;
        srcRowM = 0xFFFFFFFFu;
        preOut  = (layer == 1) ? g_pre1 : g_pre2;
        preTagB = (layer == 1) ? TAGP1 : TAGP2;
        biasL   = (layer == 1) ? (bih1[rk] + bhh1[rk]) : (bih2[rk] + bhh2[rk]);
    }

    // ---- weights into registers: 8 gate-rows (2 units x 4 gates) x 16 ----
    float W[8][16];
#pragma unroll
    for (int u = 0; u < 2; ++u)
#pragma unroll
        for (int g = 0; g < 4; ++g) {
            const float* pr = Wmat + (size_t)((g << 10) + j0 + u) * HD;
#pragma unroll
            for (int i = 0; i < 16; ++i) W[u * 4 + g][i] = pr[(i << 6) + lane];
        }

    float wi0[8];
    if (isH && layer == 0) {
#pragma unroll
        for (int kk = 0; kk < 8; ++kk)
            wi0[kk] = wih0[(size_t)(((kk & 3) << 10) + j0 + (kk >> 2)) * 64 + lane];
    }

    float c = 0.f;
    const int sb = wave << 8;    // this wave's staging quarter [sb, sb+256)

    for (int t = 0; t < T_STEPS; ++t) {
        const int p = t & 1;
        u64 pre = 0; float xv = 0.f;

        // ---- staging (h-role: own h[t-1]; x-role: upstream h[t]) ----
        if (isH) {
            if (layer == 0) {
                xv = seq[(size_t)t * 64 + lane];
            } else {
                // early preact probe: one 64B line, >=1 slot of slack
                pre = __hip_atomic_load(preIn + (size_t)t * 4096 + (j0 << 2) + k,
                                        __ATOMIC_RELAXED, __HIP_MEMORY_SCOPE_AGENT);
            }
            if (t > 0) {
                uint32_t todo = 0xFu;
                const uint32_t htag = myTagB + (uint32_t)(t - 1);
                const u64* hrow = srcBuf + (size_t)((uint32_t)(t - 1) & srcRowM) * HD;
                while (__any(todo)) {
#pragma unroll
                    for (int i = 0; i < 4; ++i) if (todo & (1u << i)) {
                        const u64 u = __hip_atomic_load(hrow + sb + (i << 6) + lane,
                                                        __ATOMIC_RELAXED, __HIP_MEMORY_SCOPE_AGENT);
                        if ((uint32_t)(u >> 32) == htag) {
                            s_buf[p][sb + (i << 6) + lane] = __uint_as_float((uint32_t)u);
                            todo &= ~(1u << i);
                        }
                    }
                }
            }
        } else {
            uint32_t todo = 0xFu;
            const uint32_t xtag = srcTagB + (uint32_t)t;
            const u64* xrow = srcBuf + (size_t)t * HD;
            while (__any(todo)) {
#pragma unroll
                for (int i = 0; i < 4; ++i) if (todo & (1u << i)) {
                    const u64 u = __hip_atomic_load(xrow + sb + (i << 6) + lane,
                                                    __ATOMIC_RELAXED, __HIP_MEMORY_SCOPE_AGENT);
                    if ((uint32_t)(u >> 32) == xtag) {
                        s_buf[p][sb + (i << 6) + lane] = __uint_as_float((uint32_t)u);
                        todo &= ~(1u << i);
                    }
                }
            }
        }
        __syncthreads();

        // ---- 8 gate dot-products (per-lane partials) ----
        float a0, a1, a2, a3, a4, a5, a6, a7;
        if (isH && layer == 0) {
            a0 = wi0[0] * xv; a1 = wi0[1] * xv; a2 = wi0[2] * xv; a3 = wi0[3] * xv;
            a4 = wi0[4] * xv; a5 = wi0[5] * xv; a6 = wi0[6] * xv; a7 = wi0[7] * xv;
        } else {
            a0 = a1 = a2 = a3 = a4 = a5 = a6 = a7 = 0.f;
        }
        if (!isH || t > 0) {
            const float* sp = s_buf[p];
#pragma unroll
            for (int i = 0; i < 16; ++i) {
                const float hv = sp[(i << 6) | lane];
                a0 = __fmaf_rn(W[0][i], hv, a0);
                a1 = __fmaf_rn(W[1][i], hv, a1);
                a2 = __fmaf_rn(W[2][i], hv, a2);
                a3 = __fmaf_rn(W[3][i], hv, a3);
                a4 = __fmaf_rn(W[4][i], hv, a4);
                a5 = __fmaf_rn(W[5][i], hv, a5);
                a6 = __fmaf_rn(W[6][i], hv, a6);
                a7 = __fmaf_rn(W[7][i], hv, a7);
            }
        }

        // ---- scatter-butterfly reduce: lane l ends with 64-lane sum of acc (l&7) ----
        float e;
        {
            const int l1 = lane & 1, l2 = lane & 2, l4 = lane & 4;
            const float s0 = __shfl_xor(a0, 1, 64), s1 = __shfl_xor(a1, 1, 64);
            const float s2 = __shfl_xor(a2, 1, 64), s3 = __shfl_xor(a3, 1, 64);
            const float s4 = __shfl_xor(a4, 1, 64), s5 = __shfl_xor(a5, 1, 64);
            const float s6 = __shfl_xor(a6, 1, 64), s7 = __shfl_xor(a7, 1, 64);
            const float c0 = l1 ? (a1 + s1) : (a0 + s0);
            const float c1 = l1 ? (a3 + s3) : (a2 + s2);
            const float c2 = l1 ? (a5 + s5) : (a4 + s4);
            const float c3 = l1 ? (a7 + s7) : (a6 + s6);
            const float u0 = __shfl_xor(c0, 2, 64), u1 = __shfl_xor(c1, 2, 64);
            const float u2 = __shfl_xor(c2, 2, 64), u3 = __shfl_xor(c3, 2, 64);
            const float d0 = l2 ? (c1 + u1) : (c0 + u0);
            const float d1 = l2 ? (c3 + u3) : (c2 + u2);
            const float v0 = __shfl_xor(d0, 4, 64), v1 = __shfl_xor(d1, 4, 64);
            e = l4 ? (d1 + v1) : (d0 + v0);
            e += __shfl_xor(e, 8, 64);
            e += __shfl_xor(e, 16, 64);
            e += __shfl_xor(e, 32, 64);
        }

        // ---- epilogue ----
        if (isH) {
            float val;
            if (layer == 0) {
                val = e + biasL;
            } else {
                const uint32_t want = preTagB + (uint32_t)t;
                bool bad = ((uint32_t)(pre >> 32) != want);
                while (__any(bad)) {
                    if (bad) {
                        pre = __hip_atomic_load(preIn + (size_t)t * 4096 + (j0 << 2) + k,
                                                __ATOMIC_RELAXED, __HIP_MEMORY_SCOPE_AGENT);
                        bad = ((uint32_t)(pre >> 32) != want);
                    }
                }
                val = e + __uint_as_float((uint32_t)pre);   // preact holds Wih.x + b_ih + b_hh
            }
            // gate nonlinearity: k&3 == 2 is the g-gate (tanh), others sigmoid
            const float av = ((lane & 3) == 2) ? ftanh(val) : fsig(val);
            const int gb = lane & ~3;
            const float iv = __shfl(av, gb + 0, 64);
            const float fv = __shfl(av, gb + 1, 64);
            const float gv = __shfl(av, gb + 2, 64);
            const float ov = __shfl(av, gb + 3, 64);
            c = __fmaf_rn(fv, c, iv * gv);
            const float h = ov * ftanh(c);
            if (lane < 8 && (lane & 3) == 0) {
                const u64 slot = ((u64)(myTagB + (uint32_t)t) << 32)
                               | (u64)__float_as_uint(h);
                __hip_atomic_store(hOut + (size_t)((uint32_t)t & outRowM) * HD + (j0 + (lane >> 2)),
                                   slot, __ATOMIC_RELAXED, __HIP_MEMORY_SCOPE_AGENT);
            }
        } else {
            const float val = e + biasL;
            if (lane < 8) {
                const u64 slot = ((u64)(preTagB + (uint32_t)t) << 32)
                               | (u64)__float_as_uint(val);
                __hip_atomic_store(preOut + (size_t)t * 4096 + (j0 << 2) + lane,
                                   slot, __ATOMIC_RELAXED, __HIP_MEMORY_SCOPE_AGENT);
            }
        }
    }
}

__global__ __launch_bounds__(256)
void final_kernel(const float* __restrict__ w_lin,
                  const float* __restrict__ b_lin,
                  float*       __restrict__ out)
{
    __shared__ float red[256];
    const int tid = threadIdx.x;
    const u64* hrow = g_ring + (size_t)((T_STEPS - 1) & (RINGR - 1)) * HD;
    float s = 0.f;
#pragma unroll
    for (int i = 0; i < 4; ++i) {
        const int kk = tid + 256 * i;
        s += __uint_as_float((uint32_t)hrow[kk]) * w_lin[kk];
    }
    red[tid] = s;
    __syncthreads();
    for (int o = 128; o > 0; o >>= 1) {
        if (tid < o) red[tid] += red[tid + o];
        __syncthreads();
    }
    if (tid == 0) out[0] = red[0] + b_lin[0];
}

extern "C" void kernel_launch(void* const* d_in, const int* in_sizes, int n_in,
                              void* d_out, int out_size, void* d_ws, size_t ws_size,
                              hipStream_t stream)
{
    (void)in_sizes; (void)n_in; (void)out_size; (void)d_ws; (void)ws_size;

    const float* seq   = (const float*)d_in[0];
    const float* w_ih0 = (const float*)d_in[1];
    const float* w_hh0 = (const float*)d_in[2];
    const float* b_ih0 = (const float*)d_in[3];
    const float* b_hh0 = (const float*)d_in[4];
    const float* w_ih1 = (const float*)d_in[5];
    const float* w_hh1 = (const float*)d_in[6];
    const float* b_ih1 = (const float*)d_in[7];
    const float* b_hh1 = (const float*)d_in[8];
    const float* w_ih2 = (const float*)d_in[9];
    const float* w_hh2 = (const float*)d_in[10];
    const float* b_ih2 = (const float*)d_in[11];
    const float* b_hh2 = (const float*)d_in[12];
    const float* w_lin = (const float*)d_in[13];
    const float* b_lin = (const float*)d_in[14];

    // Tag hygiene (previous replay left matching tags in the buffers).
    zero_bufs<<<dim3(2048), dim3(256), 0, stream>>>();

    // Blocks [0,384) = h-role (128/layer); [384,640) = x-role (128 for L1, 128 for L2).
    fused_scan<<<dim3(640), dim3(256), 0, stream>>>(
        seq,
        w_ih0, w_hh0, b_ih0, b_hh0,
        w_ih1, w_hh1, b_ih1, b_hh1,
        w_ih2, w_hh2, b_ih2, b_hh2);

    final_kernel<<<dim3(1), dim3(256), 0, stream>>>(w_lin, b_lin, (float*)d_out);
}